// Round 9
// baseline (406.950 us; speedup 1.0000x reference)
//
#include <hip/hip_runtime.h>
#include <hip/hip_bf16.h>
#include <stdint.h>

#define N_TOK 8192
#define DIM   1024
#define NEXP  8
#define CAP   1024

typedef __attribute__((ext_vector_type(8))) short bf16x8;
typedef __attribute__((ext_vector_type(4))) float f32x4;

static __device__ __forceinline__ unsigned short f2bf(float f) {
  unsigned int u = __float_as_uint(f);
  u += 0x7FFFu + ((u >> 16) & 1u);          // round-to-nearest-even
  return (unsigned short)(u >> 16);
}

// async global->LDS, 16B per lane. LDS dest must be wave-uniform base (HW adds lane*16).
static __device__ __forceinline__ void gld_lds16(const void* g, void* l) {
  __builtin_amdgcn_global_load_lds(
      (__attribute__((address_space(1))) void*)(uintptr_t)g,
      (__attribute__((address_space(3))) void*)(unsigned int)(uintptr_t)l,
      16, 0, 0);
}

// ======== Fused router + ordered scan (last-block-done pattern, 2048 blocks) ============
__global__ __launch_bounds__(256)
void router_scan_kernel(const float* __restrict__ x, const float* __restrict__ Wr,
                        const float* __restrict__ br, float* __restrict__ gate,
                        int* __restrict__ idxs, int* __restrict__ slot_token,
                        int* __restrict__ keep, unsigned int* __restrict__ rs_ctr) {
  const int t = threadIdx.x, lane = t & 63, w = t >> 6;
  const int tok = blockIdx.x * 4 + w;         // 2048 blocks x 4 waves = 8192 tokens
  {
    const float* xr = x + (size_t)tok * DIM;
    double acc[8] = {0,0,0,0,0,0,0,0};
    #pragma unroll 4
    for (int j = 0; j < 16; ++j) {
      const int d = j * 64 + lane;
      const double xv = (double)xr[d];
      const float4 wa = *(const float4*)(Wr + d * 8);
      const float4 wb = *(const float4*)(Wr + d * 8 + 4);
      acc[0] += xv * (double)wa.x;  acc[1] += xv * (double)wa.y;
      acc[2] += xv * (double)wa.z;  acc[3] += xv * (double)wa.w;
      acc[4] += xv * (double)wb.x;  acc[5] += xv * (double)wb.y;
      acc[6] += xv * (double)wb.z;  acc[7] += xv * (double)wb.w;
    }
    #pragma unroll
    for (int off = 1; off < 64; off <<= 1) {
      #pragma unroll
      for (int e = 0; e < 8; ++e) acc[e] += __shfl_xor(acc[e], off);
    }
    if (lane == 0) {
      double lg[8];
      #pragma unroll
      for (int e = 0; e < 8; ++e) lg[e] = acc[e] + (double)br[e];
      int best = 0; double bm = lg[0];
      #pragma unroll
      for (int e = 1; e < 8; ++e) { if (lg[e] > bm) { bm = lg[e]; best = e; } }
      double s = 0.0;
      #pragma unroll
      for (int e = 0; e < 8; ++e) s += exp(lg[e] - bm);
      gate[tok] = (float)(1.0 / s);           // max softmax prob
      idxs[tok] = best;
    }
  }

  // ---- finisher election ----
  __shared__ int is_last;
  __syncthreads();
  if (t == 0) {
    __threadfence();                          // release this block's gate/idxs writes
    unsigned int old = atomicAdd(rs_ctr, 1u);
    is_last = (old == 2047u) ? 1 : 0;
  }
  __syncthreads();
  if (!is_last) return;
  __threadfence();                            // acquire: see all blocks' idxs

  // ---- ordered scan (single block, 256 thr x 32 tokens) ----
  __shared__ int wtot[4][8];
  __shared__ int rbuf[256][8];
  for (int j = t; j < NEXP * CAP; j += 256) slot_token[j] = -1;
  __syncthreads();
  const int base = t * 32;
  #pragma unroll
  for (int e = 0; e < 8; ++e) rbuf[t][e] = 0;
  for (int j = 0; j < 32; ++j) rbuf[t][idxs[base + j]] += 1;
  int cnt[8], incl[8];
  #pragma unroll
  for (int e = 0; e < 8; ++e) {
    cnt[e] = rbuf[t][e];
    int v = cnt[e];
    #pragma unroll
    for (int off = 1; off < 64; off <<= 1) {
      int u = __shfl_up(v, off);
      if (lane >= off) v += u;
    }
    incl[e] = v;                              // inclusive within-wave prefix
  }
  if (lane == 63) {
    #pragma unroll
    for (int e = 0; e < 8; ++e) wtot[w][e] = incl[e];
  }
  __syncthreads();
  if (t == 0) {                               // exclusive scan over 4 wave totals
    int run[8] = {0,0,0,0,0,0,0,0};
    for (int ww = 0; ww < 4; ++ww) {
      #pragma unroll
      for (int e = 0; e < 8; ++e) { int tmp = wtot[ww][e]; wtot[ww][e] = run[e]; run[e] += tmp; }
    }
  }
  __syncthreads();
  #pragma unroll
  for (int e = 0; e < 8; ++e) rbuf[t][e] = wtot[w][e] + incl[e] - cnt[e];
  for (int j = 0; j < 32; ++j) {
    const int n = base + j;
    const int e = idxs[n];
    const int r = ++rbuf[t][e];               // 1-based position in token order
    const int kept = (r < CAP) ? 1 : 0;
    keep[n] = kept;
    if (kept) slot_token[e * CAP + r] = n;    // slot 0 never used
  }
}

// ======== Fused utility (weight fp32->bf16^T 64x64 tiles / gather / zerofill) ===========
__global__ __launch_bounds__(256)
void util_kernel(const float* __restrict__ W1, const float* __restrict__ W2,
                 unsigned short* __restrict__ W1T, unsigned short* __restrict__ W2T,
                 const float* __restrict__ x, const float* __restrict__ gate,
                 const int* __restrict__ slot_token, const int* __restrict__ keep,
                 unsigned short* __restrict__ Xe, float* __restrict__ out) {
  const int t = threadIdx.x;
  if (blockIdx.x < 4096) {
    __shared__ float tile[64][65];
    const int mi = blockIdx.x >> 8;           // 0..7: W1 expert, 8..15: W2 expert
    const int tz = blockIdx.x & 255;
    const int tr = tz >> 4, tc = tz & 15;     // 16x16 tiles of 64x64 over 1024^2
    const float* src = (mi < 8) ? (W1 + (size_t)mi * DIM * DIM)
                                : (W2 + (size_t)(mi - 8) * DIM * DIM);
    unsigned short* dst = (mi < 8) ? (W1T + (size_t)mi * DIM * DIM)
                                   : (W2T + (size_t)(mi - 8) * DIM * DIM);
    #pragma unroll
    for (int q = 0; q < 4; ++q) {             // read 16 rows/iter, 256B chunks
      const int row = q * 16 + (t >> 4);
      const int c4  = (t & 15) * 4;
      const float4 v = *(const float4*)(src + (size_t)(tr * 64 + row) * DIM + tc * 64 + c4);
      tile[row][c4 + 0] = v.x; tile[row][c4 + 1] = v.y;
      tile[row][c4 + 2] = v.z; tile[row][c4 + 3] = v.w;
    }
    __syncthreads();
    #pragma unroll
    for (int p = 0; p < 2; ++p) {             // write 32 dst rows/iter, 128B chunks
      const int n  = p * 32 + (t >> 3);       // dst row = src col
      const int k0 = (t & 7) * 8;             // dst cols = src rows
      bf16x8 o;
      #pragma unroll
      for (int j = 0; j < 8; ++j) o[j] = (short)f2bf(tile[k0 + j][n]);
      *(bf16x8*)(dst + (size_t)(tc * 64 + n) * DIM + tr * 64 + k0) = o;
    }
  } else if (blockIdx.x < 4096 + NEXP * CAP) {
    const int s = blockIdx.x - 4096;
    const int n = slot_token[s];
    if (n < 0) return;                        // empty slot: poison row never reaches output
    const float g = gate[n];
    const float4 v = ((const float4*)(x + (size_t)n * DIM))[t];
    ushort4 o;
    o.x = f2bf(v.x * g); o.y = f2bf(v.y * g); o.z = f2bf(v.z * g); o.w = f2bf(v.w * g);
    ((ushort4*)(Xe + (size_t)s * DIM))[t] = o;
  } else {
    const int n = blockIdx.x - (4096 + NEXP * CAP);
    if (keep[n]) return;                      // kept rows fully written by gemm2 scatter
    float4 z = {0.f, 0.f, 0.f, 0.f};
    ((float4*)(out + (size_t)n * DIM))[t] = z;
  }
}

// ======== Fused GEMM pair: gemm1 tile -> panel signal -> spin -> gemm2 tile =============
// Group (e,bm) = 8 blocks (bn=0..7) at bids bm*64 + bn*8 + e: one contiguous 64-bid
// window -> co-dispatched; spin happens AFTER own gemm1 => deadlock-free.
// panel_ctr is e*8+bm (64 groups) — R8's e*4+bm collided groups (the replay race).
template <int OP>
static __device__ __forceinline__ void gemm_body(
    unsigned short* Asub, unsigned short* Bsub,            // [3*4096] ushort each
    const unsigned short* __restrict__ A, const unsigned short* __restrict__ Bt,
    const float* __restrict__ bias, const int* __restrict__ slot_token,
    const float* __restrict__ gate, unsigned short* __restrict__ Hout,
    float* __restrict__ Cout) {
  const int bid = blockIdx.x;
  const int e  = bid & 7;
  const int tt = bid >> 3;
  const int bm = tt >> 3;
  const int bn = tt & 7;
  const int tid = threadIdx.x, lane = tid & 63, w = tid >> 6;
  const int wr = w >> 1, wc = w & 1;

  const unsigned short* Ae = A  + (size_t)(e * CAP + bm * 128) * DIM;
  const unsigned short* Be = Bt + (size_t)e * DIM * DIM + (size_t)(bn * 128) * DIM;

  const int srow = lane >> 2;
  const int scol = (((lane & 3) ^ ((lane >> 3) & 3)) * 8);   // involution src k-slot swizzle
  const int lrow = lane & 15;
  const int kof  = (((lane >> 4) ^ ((lrow >> 1) & 3)) * 8);  // matching read k-slot swizzle

  f32x4 acc[4][4] = {};

  auto stage = [&](int buf, int kt) {
    const int k0 = kt * 32;
    #pragma unroll
    for (int c = 0; c < 2; ++c) {
      const int chunk = w + c * 4;                           // wave-uniform
      const int r = chunk * 16 + srow;
      gld_lds16(Ae + (size_t)r * DIM + k0 + scol, &Asub[buf * 4096 + chunk * 512]);
      gld_lds16(Be + (size_t)r * DIM + k0 + scol, &Bsub[buf * 4096 + chunk * 512]);
    }
  };
  auto compute = [&](int buf) {
    bf16x8 af[4], bfr[4];
    #pragma unroll
    for (int m = 0; m < 4; ++m)
      af[m] = *(const bf16x8*)&Asub[buf * 4096 + (wr * 64 + m * 16 + lrow) * 32 + kof];
    #pragma unroll
    for (int n = 0; n < 4; ++n)
      bfr[n] = *(const bf16x8*)&Bsub[buf * 4096 + (wc * 64 + n * 16 + lrow) * 32 + kof];
    #pragma unroll
    for (int m = 0; m < 4; ++m)
      #pragma unroll
      for (int n = 0; n < 4; ++n)
        acc[m][n] = __builtin_amdgcn_mfma_f32_16x16x32_bf16(af[m], bfr[n], acc[m][n], 0, 0, 0);
  };

  stage(0, 0);
  stage(1, 1);
  asm volatile("s_waitcnt vmcnt(4)" ::: "memory");
  __builtin_amdgcn_s_barrier();
  int b0 = 0, b1 = 1, b2 = 2;
  for (int kt = 0; kt < 32; ++kt) {
    if (kt < 30) stage(b2, kt + 2);
    compute(b0);
    if (kt == 31) break;
    if (kt < 30) asm volatile("s_waitcnt vmcnt(4)" ::: "memory");
    else         asm volatile("s_waitcnt vmcnt(0)" ::: "memory");
    __builtin_amdgcn_s_barrier();
    const int tb = b0; b0 = b1; b1 = b2; b2 = tb;
  }

  if (OP == 1) {
    // Coalesced H epilogue: per-m LDS bounce (32x128 bf16 slab), 256B row flushes.
    unsigned short* slab = Asub;                             // 8KB of the 12KB buffer
    #pragma unroll
    for (int m = 0; m < 4; ++m) {
      __syncthreads();                                       // slab free (also post-K-loop)
      #pragma unroll
      for (int n = 0; n < 4; ++n) {
        const int col = wc * 64 + n * 16 + lrow;
        const float bv = bias[e * DIM + bn * 128 + col];
        #pragma unroll
        for (int i = 0; i < 4; ++i) {
          const int lr = wr * 16 + (lane >> 4) * 4 + i;      // 0..31
          float v = acc[m][n][i] + bv;
          v = v > 0.0f ? v : 0.0f;
          slab[lr * 128 + col] = f2bf(v);
        }
      }
      __syncthreads();
      #pragma unroll
      for (int p = 0; p < 2; ++p) {                          // 256 thr x 16B x 2 = 8KB
        const int lr = (tid >> 4) + p * 16;
        const int c0 = (tid & 15) * 8;
        const int grow = bm * 128 + (lr >> 4) * 64 + m * 16 + (lr & 15);
        *(bf16x8*)(Hout + (size_t)(e * CAP + grow) * DIM + bn * 128 + c0) =
            *(const bf16x8*)&slab[lr * 128 + c0];
      }
    }
  } else {
    float bv[4];
    #pragma unroll
    for (int n = 0; n < 4; ++n)
      bv[n] = bias[e * DIM + bn * 128 + wc * 64 + n * 16 + lrow];
    #pragma unroll
    for (int m = 0; m < 4; ++m) {
      const int r0 = bm * 128 + wr * 64 + m * 16 + (lane >> 4) * 4;
      #pragma unroll
      for (int i = 0; i < 4; ++i) {
        const int tok = slot_token[e * CAP + r0 + i];
        if (tok >= 0) {
          const float g = gate[tok];
          float* orow = Cout + (size_t)tok * DIM;
          #pragma unroll
          for (int n = 0; n < 4; ++n) {
            const int col = bn * 128 + wc * 64 + n * 16 + lrow;
            orow[col] = g * (acc[m][n][i] + bv[n]);
          }
        }
      }
    }
  }
}

__global__ __launch_bounds__(256)
void moe_gemm_kernel(const unsigned short* __restrict__ Xe,
                     const unsigned short* __restrict__ W1T, const float* __restrict__ b1,
                     const unsigned short* __restrict__ W2T, const float* __restrict__ b2,
                     unsigned short* __restrict__ Hh, float* __restrict__ out,
                     const int* __restrict__ slot_token, const float* __restrict__ gate,
                     unsigned int* __restrict__ panel_ctr) {
  __shared__ unsigned short Asub[3 * 4096];
  __shared__ unsigned short Bsub[3 * 4096];
  const int e  = blockIdx.x & 7;
  const int bm = (blockIdx.x >> 3) >> 3;      // 0..7
  const int tid = threadIdx.x;

  gemm_body<1>(Asub, Bsub, Xe, W1T, b1, nullptr, nullptr, Hh, nullptr);

  __shared__ int ready;
  __syncthreads();
  __threadfence();                            // release my H-panel stores
  if (tid == 0) {
    atomicAdd(&panel_ctr[e * 8 + bm], 1u);    // 64 distinct groups (R8 bug: e*4+bm collided)
    while (atomicAdd(&panel_ctr[e * 8 + bm], 0u) < 8u) { __builtin_amdgcn_s_sleep(8); }
    ready = 1;
  }
  __syncthreads();
  (void)ready;
  __threadfence();                            // acquire: see the whole group's H panel

  gemm_body<2>(Asub, Bsub, Hh, W2T, b2, slot_token, gate, nullptr, out);
}

extern "C" void kernel_launch(void* const* d_in, const int* in_sizes, int n_in,
                              void* d_out, int out_size, void* d_ws, size_t ws_size,
                              hipStream_t stream) {
  const float* x  = (const float*)d_in[0];
  const float* Wr = (const float*)d_in[1];
  const float* br = (const float*)d_in[2];
  const float* W1 = (const float*)d_in[3];
  const float* b1 = (const float*)d_in[4];
  const float* W2 = (const float*)d_in[5];
  const float* b2 = (const float*)d_in[6];
  float* out = (float*)d_out;

  char* ws = (char*)d_ws;
  unsigned short* Xe  = (unsigned short*)(ws);                                  // 16 MB
  unsigned short* Hh  = (unsigned short*)(ws + (size_t)16 * 1024 * 1024);       // 16 MB
  unsigned short* W1T = (unsigned short*)(ws + (size_t)32 * 1024 * 1024);       // 16 MB
  unsigned short* W2T = (unsigned short*)(ws + (size_t)48 * 1024 * 1024);       // 16 MB
  float* gate     = (float*)(ws + (size_t)64 * 1024 * 1024);                    // 32 KB
  int*   idxs     = (int*)  (ws + (size_t)64 * 1024 * 1024 + 32768);            // 32 KB
  int*   slot_tok = (int*)  (ws + (size_t)64 * 1024 * 1024 + 65536);            // 32 KB
  int*   keep     = (int*)  (ws + (size_t)64 * 1024 * 1024 + 98304);            // 32 KB
  unsigned int* ctrs = (unsigned int*)(ws + (size_t)64 * 1024 * 1024 + 131072); // 512 B
  unsigned int* rs_ctr    = ctrs;            // [0]
  unsigned int* panel_ctr = ctrs + 16;       // [16..79]: 8 experts x 8 panels

  hipMemsetAsync(ctrs, 0, 512, stream);      // counters must start at 0 every call
  router_scan_kernel<<<2048, 256, 0, stream>>>(x, Wr, br, gate, idxs, slot_tok, keep, rs_ctr);
  util_kernel<<<20480, 256, 0, stream>>>(W1, W2, W1T, W2T, x, gate, slot_tok, keep, Xe, out);
  moe_gemm_kernel<<<512, 256, 0, stream>>>(Xe, W1T, b1, W2T, b2, Hh, out, slot_tok, gate,
                                           panel_ctr);
}

// Round 11
// 231.640 us; speedup vs baseline: 1.7568x; 1.7568x over previous
//
#include <hip/hip_runtime.h>
#include <hip/hip_bf16.h>
#include <stdint.h>

#define N_TOK 8192
#define DIM   1024
#define NEXP  8
#define CAP   1024

typedef __attribute__((ext_vector_type(8))) short bf16x8;
typedef __attribute__((ext_vector_type(4))) float f32x4;

static __device__ __forceinline__ unsigned short f2bf(float f) {
  unsigned int u = __float_as_uint(f);
  u += 0x7FFFu + ((u >> 16) & 1u);          // round-to-nearest-even
  return (unsigned short)(u >> 16);
}

// async global->LDS, 16B per lane. LDS dest must be wave-uniform base (HW adds lane*16).
static __device__ __forceinline__ void gld_lds16(const void* g, void* l) {
  __builtin_amdgcn_global_load_lds(
      (__attribute__((address_space(1))) void*)(uintptr_t)g,
      (__attribute__((address_space(3))) void*)(unsigned int)(uintptr_t)l,
      16, 0, 0);
}

// ---------------- Router: logits = x@Wr + br ; gate = max softmax prob ; idx = argmax ----
__global__ void router_kernel(const float* __restrict__ x, const float* __restrict__ Wr,
                              const float* __restrict__ br, float* __restrict__ gate,
                              int* __restrict__ idxs) {
  const int wid  = (blockIdx.x * blockDim.x + threadIdx.x) >> 6;   // token id (1 wave/token)
  const int lane = threadIdx.x & 63;
  const float* xr = x + (size_t)wid * DIM;
  double acc[8] = {0,0,0,0,0,0,0,0};
  #pragma unroll 4
  for (int j = 0; j < 16; ++j) {
    const int d = j * 64 + lane;
    const double xv = (double)xr[d];
    const float4 wa = *(const float4*)(Wr + d * 8);
    const float4 wb = *(const float4*)(Wr + d * 8 + 4);
    acc[0] += xv * (double)wa.x;  acc[1] += xv * (double)wa.y;
    acc[2] += xv * (double)wa.z;  acc[3] += xv * (double)wa.w;
    acc[4] += xv * (double)wb.x;  acc[5] += xv * (double)wb.y;
    acc[6] += xv * (double)wb.z;  acc[7] += xv * (double)wb.w;
  }
  #pragma unroll
  for (int off = 1; off < 64; off <<= 1) {
    #pragma unroll
    for (int e = 0; e < 8; ++e) acc[e] += __shfl_xor(acc[e], off);
  }
  if (lane == 0) {
    double lg[8];
    #pragma unroll
    for (int e = 0; e < 8; ++e) lg[e] = acc[e] + (double)br[e];
    int best = 0; double bm = lg[0];
    #pragma unroll
    for (int e = 1; e < 8; ++e) { if (lg[e] > bm) { bm = lg[e]; best = e; } }  // first-wins ties
    double s = 0.0;
    #pragma unroll
    for (int e = 0; e < 8; ++e) s += exp(lg[e] - bm);
    gate[wid] = (float)(1.0 / s);   // max softmax prob
    idxs[wid] = best;
  }
}

// ---------------- Ordered per-expert position scan (single block, 1024 thr, 8 tok/thr) ----
__global__ void scan_kernel(const int* __restrict__ idxs, int* __restrict__ slot_token,
                            int* __restrict__ keep) {
  __shared__ int wtot[16][8];
  const int t = threadIdx.x, lane = t & 63, w = t >> 6;
  #pragma unroll
  for (int j = 0; j < 8; ++j) slot_token[t * 8 + j] = -1;   // visible after barriers below
  int myidx[8];
  #pragma unroll
  for (int j = 0; j < 8; ++j) myidx[j] = idxs[t * 8 + j];
  int cnt[8], incl[8];
  #pragma unroll
  for (int e = 0; e < 8; ++e) {
    int c = 0;
    #pragma unroll
    for (int j = 0; j < 8; ++j) c += (myidx[j] == e) ? 1 : 0;
    cnt[e] = c;
    int v = c;
    #pragma unroll
    for (int off = 1; off < 64; off <<= 1) {
      int u = __shfl_up(v, off);
      if (lane >= off) v += u;
    }
    incl[e] = v;                       // inclusive within-wave prefix
  }
  if (lane == 63) {
    #pragma unroll
    for (int e = 0; e < 8; ++e) wtot[w][e] = incl[e];
  }
  __syncthreads();
  if (t == 0) {                        // serial exclusive scan over 16 wave totals
    int run[8] = {0,0,0,0,0,0,0,0};
    for (int ww = 0; ww < 16; ++ww) {
      #pragma unroll
      for (int e = 0; e < 8; ++e) {
        int tmp = wtot[ww][e]; wtot[ww][e] = run[e]; run[e] += tmp;
      }
    }
  }
  __syncthreads();
  #pragma unroll
  for (int e = 0; e < 8; ++e) {
    int r = wtot[w][e] + incl[e] - cnt[e];   // tokens of expert e before my chunk
    #pragma unroll
    for (int j = 0; j < 8; ++j) {
      if (myidx[j] == e) {
        ++r;                                  // 1-based pos (slot 0 never used)
        const int kept = (r < CAP) ? 1 : 0;
        keep[t * 8 + j] = kept;
        if (kept) slot_token[e * CAP + r] = t * 8 + j;
      }
    }
  }
}

// ======== Fused utility (weight fp32->bf16^T 64x64 tiles / gather / zerofill) ===========
//   blocks [0, 4096):        wt: 16 matrices x 256 tiles of 64x64
//   blocks [4096, 12288):    gather Xe[slot,:] = bf16(gate[n]*x[n,:])
//   blocks [12288, 20480):   zero-fill out rows of dropped tokens
__global__ __launch_bounds__(256)
void util_kernel(const float* __restrict__ W1, const float* __restrict__ W2,
                 unsigned short* __restrict__ W1T, unsigned short* __restrict__ W2T,
                 const float* __restrict__ x, const float* __restrict__ gate,
                 const int* __restrict__ slot_token, const int* __restrict__ keep,
                 unsigned short* __restrict__ Xe, float* __restrict__ out) {
  const int t = threadIdx.x;
  if (blockIdx.x < 4096) {
    __shared__ float tile[64][65];
    const int mi = blockIdx.x >> 8;           // 0..7: W1 expert, 8..15: W2 expert
    const int tz = blockIdx.x & 255;
    const int tr = tz >> 4, tc = tz & 15;     // 16x16 tiles of 64x64 over 1024^2
    const float* src = (mi < 8) ? (W1 + (size_t)mi * DIM * DIM)
                                : (W2 + (size_t)(mi - 8) * DIM * DIM);
    unsigned short* dst = (mi < 8) ? (W1T + (size_t)mi * DIM * DIM)
                                   : (W2T + (size_t)(mi - 8) * DIM * DIM);
    #pragma unroll
    for (int q = 0; q < 4; ++q) {             // read 16 rows/iter, 256B chunks
      const int row = q * 16 + (t >> 4);
      const int c4  = (t & 15) * 4;
      const float4 v = *(const float4*)(src + (size_t)(tr * 64 + row) * DIM + tc * 64 + c4);
      tile[row][c4 + 0] = v.x; tile[row][c4 + 1] = v.y;
      tile[row][c4 + 2] = v.z; tile[row][c4 + 3] = v.w;
    }
    __syncthreads();
    #pragma unroll
    for (int p = 0; p < 2; ++p) {             // write 32 dst rows/iter, 128B chunks
      const int n  = p * 32 + (t >> 3);       // dst row = src col
      const int k0 = (t & 7) * 8;             // dst cols = src rows
      bf16x8 o;
      #pragma unroll
      for (int j = 0; j < 8; ++j) o[j] = (short)f2bf(tile[k0 + j][n]);
      *(bf16x8*)(dst + (size_t)(tc * 64 + n) * DIM + tr * 64 + k0) = o;
    }
  } else if (blockIdx.x < 4096 + NEXP * CAP) {
    const int s = blockIdx.x - 4096;
    const int n = slot_token[s];
    if (n < 0) return;                        // empty slot: poison row never reaches output
    const float g = gate[n];
    const float4 v = ((const float4*)(x + (size_t)n * DIM))[t];
    ushort4 o;
    o.x = f2bf(v.x * g); o.y = f2bf(v.y * g); o.z = f2bf(v.z * g); o.w = f2bf(v.w * g);
    ((ushort4*)(Xe + (size_t)s * DIM))[t] = o;
  } else {
    const int n = blockIdx.x - (4096 + NEXP * CAP);
    if (keep[n]) return;                      // kept rows fully written by gemm2 scatter
    float4 z = {0.f, 0.f, 0.f, 0.f};
    ((float4*)(out + (size_t)n * DIM))[t] = z;
  }
}

// ---------------- Grouped GEMM, 128x128 tile, BK=32, 16x16x32 bf16 MFMA ------------------
// 3-buffer LDS ring, counted s_waitcnt vmcnt(4) + raw s_barrier; involution k-slot
// swizzle on staging source + ds_read. Separate launches (kernel boundary = the flush;
// R9 proved in-kernel fences cost ~90us). e = bid&7 pins each expert to one XCD.
// OP==1: H = relu(Xe @ W1 + b1) -> bf16 via coalesced LDS-bounce epilogue (256B rows).
// OP==2: out[token] = gate*(H @ W2 + b2) scatter (64B row chunks).
template <int OP>
__global__ __launch_bounds__(256)
void gemm_kernel(const unsigned short* __restrict__ A,    // [E*CAP][DIM] bf16
                 const unsigned short* __restrict__ Bt,   // [E][DIM][DIM] bf16 (B^T rows=N)
                 const float* __restrict__ bias,          // [E][DIM]
                 const int* __restrict__ slot_token,      // OP==2
                 const float* __restrict__ gate,          // OP==2
                 unsigned short* __restrict__ Hout,       // OP==1
                 float* __restrict__ Cout)                // OP==2
{
  __shared__ unsigned short Asub[3][128 * 32];
  __shared__ unsigned short Bsub[3][128 * 32];
  const int bid = blockIdx.x;
  const int e  = bid & 7;               // expert == XCD (bid%8 round-robin heuristic)
  const int tt = bid >> 3;              // 0..63 tile index within expert
  const int bm = tt >> 3;
  const int bn = tt & 7;
  const int tid = threadIdx.x, lane = tid & 63, w = tid >> 6;
  const int wr = w >> 1, wc = w & 1;

  const unsigned short* Ae = A  + (size_t)(e * CAP + bm * 128) * DIM;
  const unsigned short* Be = Bt + (size_t)e * DIM * DIM + (size_t)(bn * 128) * DIM;

  const int srow = lane >> 2;           // staging: 16 rows per 1KB chunk, 4 lanes/row
  const int scol = (((lane & 3) ^ ((lane >> 3) & 3)) * 8);   // involution src k-slot swizzle
  const int lrow = lane & 15;
  const int kof  = (((lane >> 4) ^ ((lrow >> 1) & 3)) * 8);  // matching read k-slot swizzle

  f32x4 acc[4][4] = {};

  auto stage = [&](int buf, int kt) {   // 4 gld_lds per wave (2 A + 2 B)
    const int k0 = kt * 32;
    #pragma unroll
    for (int c = 0; c < 2; ++c) {
      const int chunk = w + c * 4;                       // wave-uniform
      const int r = chunk * 16 + srow;
      gld_lds16(Ae + (size_t)r * DIM + k0 + scol, &Asub[buf][chunk * 512]);
      gld_lds16(Be + (size_t)r * DIM + k0 + scol, &Bsub[buf][chunk * 512]);
    }
  };
  auto compute = [&](int buf) {
    bf16x8 af[4], bfr[4];
    #pragma unroll
    for (int m = 0; m < 4; ++m)
      af[m] = *(const bf16x8*)&Asub[buf][(wr * 64 + m * 16 + lrow) * 32 + kof];
    #pragma unroll
    for (int n = 0; n < 4; ++n)
      bfr[n] = *(const bf16x8*)&Bsub[buf][(wc * 64 + n * 16 + lrow) * 32 + kof];
    #pragma unroll
    for (int m = 0; m < 4; ++m)
      #pragma unroll
      for (int n = 0; n < 4; ++n)
        acc[m][n] = __builtin_amdgcn_mfma_f32_16x16x32_bf16(af[m], bfr[n], acc[m][n], 0, 0, 0);
  };

  stage(0, 0);
  stage(1, 1);
  asm volatile("s_waitcnt vmcnt(4)" ::: "memory");   // tile 0 (my 4 oldest) in LDS
  __builtin_amdgcn_s_barrier();                      // everyone's tile 0 in LDS
  int b0 = 0, b1 = 1, b2 = 2;
  for (int kt = 0; kt < 32; ++kt) {
    if (kt < 30) stage(b2, kt + 2);     // issue next-next tile into the free buffer
    compute(b0);                        // consume certified tile kt
    if (kt == 31) break;
    if (kt < 30) asm volatile("s_waitcnt vmcnt(4)" ::: "memory");  // tile kt+1 (mine) done
    else         asm volatile("s_waitcnt vmcnt(0)" ::: "memory");  // tail drain
    __builtin_amdgcn_s_barrier();       // everyone done reading b0 + tile kt+1 resident
    const int tb = b0; b0 = b1; b1 = b2; b2 = tb;
  }

  if (OP == 1) {
    // Coalesced H epilogue: per-m LDS bounce (32x128 bf16 slab), 256B row flushes.
    unsigned short* slab = &Asub[0][0];                      // 8KB scratch
    #pragma unroll
    for (int m = 0; m < 4; ++m) {
      __syncthreads();                                       // slab free (all lgkm drained)
      #pragma unroll
      for (int n = 0; n < 4; ++n) {
        const int col = wc * 64 + n * 16 + lrow;
        const float bv = bias[e * DIM + bn * 128 + col];
        #pragma unroll
        for (int i = 0; i < 4; ++i) {
          const int lr = wr * 16 + (lane >> 4) * 4 + i;      // 0..31
          float v = acc[m][n][i] + bv;
          v = v > 0.0f ? v : 0.0f;
          slab[lr * 128 + col] = f2bf(v);
        }
      }
      __syncthreads();
      #pragma unroll
      for (int p = 0; p < 2; ++p) {                          // 256 thr x 16B x 2 = 8KB
        const int lr = (tid >> 4) + p * 16;
        const int c0 = (tid & 15) * 8;
        const int grow = bm * 128 + (lr >> 4) * 64 + m * 16 + (lr & 15);
        *(bf16x8*)(Hout + (size_t)(e * CAP + grow) * DIM + bn * 128 + c0) =
            *(const bf16x8*)&slab[lr * 128 + c0];
      }
    }
  } else {
    float bv[4];
    #pragma unroll
    for (int n = 0; n < 4; ++n)
      bv[n] = bias[e * DIM + bn * 128 + wc * 64 + n * 16 + lrow];
    #pragma unroll
    for (int m = 0; m < 4; ++m) {
      const int r0 = bm * 128 + wr * 64 + m * 16 + (lane >> 4) * 4;
      #pragma unroll
      for (int i = 0; i < 4; ++i) {
        const int tok = slot_token[e * CAP + r0 + i];
        if (tok >= 0) {
          const float g = gate[tok];
          float* orow = Cout + (size_t)tok * DIM;
          #pragma unroll
          for (int n = 0; n < 4; ++n) {
            const int col = bn * 128 + wc * 64 + n * 16 + lrow;
            orow[col] = g * (acc[m][n][i] + bv[n]);
          }
        }
      }
    }
  }
}

extern "C" void kernel_launch(void* const* d_in, const int* in_sizes, int n_in,
                              void* d_out, int out_size, void* d_ws, size_t ws_size,
                              hipStream_t stream) {
  const float* x  = (const float*)d_in[0];
  const float* Wr = (const float*)d_in[1];
  const float* br = (const float*)d_in[2];
  const float* W1 = (const float*)d_in[3];
  const float* b1 = (const float*)d_in[4];
  const float* W2 = (const float*)d_in[5];
  const float* b2 = (const float*)d_in[6];
  float* out = (float*)d_out;

  char* ws = (char*)d_ws;
  unsigned short* Xe  = (unsigned short*)(ws);                                  // 16 MB
  unsigned short* Hh  = (unsigned short*)(ws + (size_t)16 * 1024 * 1024);       // 16 MB
  unsigned short* W1T = (unsigned short*)(ws + (size_t)32 * 1024 * 1024);       // 16 MB
  unsigned short* W2T = (unsigned short*)(ws + (size_t)48 * 1024 * 1024);       // 16 MB
  float* gate     = (float*)(ws + (size_t)64 * 1024 * 1024);                    // 32 KB
  int*   idxs     = (int*)  (ws + (size_t)64 * 1024 * 1024 + 32768);            // 32 KB
  int*   slot_tok = (int*)  (ws + (size_t)64 * 1024 * 1024 + 65536);            // 32 KB
  int*   keep     = (int*)  (ws + (size_t)64 * 1024 * 1024 + 98304);            // 32 KB

  router_kernel<<<2048, 256, 0, stream>>>(x, Wr, br, gate, idxs);
  scan_kernel<<<1, 1024, 0, stream>>>(idxs, slot_tok, keep);
  util_kernel<<<20480, 256, 0, stream>>>(W1, W2, W1T, W2T, x, gate, slot_tok, keep, Xe, out);
  gemm_kernel<1><<<512, 256, 0, stream>>>(Xe, W1T, b1, nullptr, nullptr, Hh, nullptr);
  gemm_kernel<2><<<512, 256, 0, stream>>>(Hh, W2T, b2, slot_tok, gate, nullptr, out);
}